// Round 2
// baseline (466.327 us; speedup 1.0000x reference)
//
#include <hip/hip_runtime.h>
#include <hip/hip_bf16.h>

#define IN_DIM  512
#define SL_DIM  256
#define M_SLOTS 64
#define TILE_R  32

typedef __attribute__((ext_vector_type(8))) short  short8;  // 8 bf16 (4 VGPRs)
typedef __attribute__((ext_vector_type(4))) float  f32x4;   // MFMA C/D

__device__ __forceinline__ short f2bf(float f) {
  union { float f; unsigned u; } v; v.f = f;
  unsigned r = (v.u + 0x7FFFu + ((v.u >> 16) & 1u)) >> 16;  // RNE
  return (short)r;
}

// packed f32x2 -> bf16x2 (v_cvt_pk_bf16_f32)
__device__ __forceinline__ unsigned cvt2(float lo, float hi) {
  union { __hip_bfloat162 h; unsigned u; } c;
  c.h = __float22bfloat162_rn(make_float2(lo, hi));
  return c.u;
}

__device__ __forceinline__ float fast_tanh(float x) {
  x = fminf(15.f, fmaxf(-15.f, x));
  float e = __expf(2.f * x);
  return (e - 1.f) / (e + 1.f);
}

// ws: enc_w bf16 [256][512] | dec_w bf16 [512][256] | mem bf16 [64][256] | memT bf16 [256][64]
__global__ void convert_weights(const float* __restrict__ enc_w,
                                const float* __restrict__ dec_w,
                                const float* __restrict__ mem,
                                short* __restrict__ encb, short* __restrict__ decb,
                                short* __restrict__ memb, short* __restrict__ memTb) {
  int i = blockIdx.x * 256 + threadIdx.x;   // grid = 512*256 = 131072 exactly
  encb[i] = f2bf(enc_w[i]);
  decb[i] = f2bf(dec_w[i]);
  if (i < M_SLOTS * SL_DIM) {
    short v = f2bf(mem[i]);
    memb[i] = v;
    memTb[(i & 255) * M_SLOTS + (i >> 8)] = v;   // memT[k][m]
  }
}

// TILE_R=32: LDS = As 5.5K + Ebuf 16.9K + Pbuf 4.6K = 26.6K -> 6 blocks/CU (24 waves, 75%)
__global__ __launch_bounds__(256, 6) void fused_kernel(
    const float* __restrict__ seq, const float* __restrict__ enc_b,
    const float* __restrict__ dec_b, const short* __restrict__ encw,
    const short* __restrict__ decw, const short* __restrict__ memb,
    const short* __restrict__ memTb, float* __restrict__ out) {
  const int tid  = threadIdx.x;
  const int wave = tid >> 6;
  const int lane = tid & 63;
  const int l16  = lane & 15;
  const int quad = lane >> 4;
  const int r0   = blockIdx.x * TILE_R;

  // As pad = 44 shorts/row (22 dwords): 22*l16 mod 32 distinct for all 16 l16 -> ~conflict-free b128
  __shared__ __align__(16) short As[2][TILE_R][44];          // double-buffered A k-slice (bf16)
  __shared__ __align__(16) short Ebuf[TILE_R][SL_DIM + 8];   // encoded, later memory (bf16)
  __shared__ __align__(16) short Pbuf[TILE_R][M_SLOTS + 8];  // attention (bf16)

  float* __restrict__ outR = out;              // reconstruction [65536][512]
  float* __restrict__ outA = out + 33554432;   // attention      [65536][64]
  float* __restrict__ outM = out + 37748736;   // memory         [65536][256]

  // ================= GEMM1: encoded = tanh(seq @ enc_w^T + b) =================
  // wave covers rows 0..31 x cols [64*wave, 64*wave+64) -> acc[2][4]
  f32x4 acc[2][4];
#pragma unroll
  for (int rb = 0; rb < 2; ++rb)
#pragma unroll
    for (int cb = 0; cb < 4; ++cb) acc[rb][cb] = (f32x4){0.f, 0.f, 0.f, 0.f};

  const int srow = tid >> 3;          // 0..31
  const int skc  = (tid & 7) * 4;     // 0..28
  const float* sp = seq + (size_t)(r0 + srow) * IN_DIM + skc;
  const short* bP[4];
#pragma unroll
  for (int cb = 0; cb < 4; ++cb)
    bP[cb] = encw + (64 * wave + 16 * cb + l16) * IN_DIM + quad * 8;

  // prologue: stage kt=0 into As[0]
  {
    float4 v = *(const float4*)(sp);
    uint2 w; w.x = cvt2(v.x, v.y); w.y = cvt2(v.z, v.w);
    *(uint2*)&As[0][srow][skc] = w;
  }

  for (int kt = 0; kt < 16; ++kt) {
    const int k0  = kt * 32;
    const int cur = kt & 1;
    // issue next A-slice global load + this iter's B loads BEFORE the barrier
    float4 vn;
    if (kt < 15) vn = *(const float4*)(sp + k0 + 32);
    short8 b[4];
#pragma unroll
    for (int cb = 0; cb < 4; ++cb)
      b[cb] = *(const short8*)(bP[cb] + k0);
    __syncthreads();                  // As[cur] visible; As[cur^1] reads (prev iter) done
    if (kt < 15) {
      uint2 w; w.x = cvt2(vn.x, vn.y); w.y = cvt2(vn.z, vn.w);
      *(uint2*)&As[cur ^ 1][srow][skc] = w;
    }
    short8 a[2];
#pragma unroll
    for (int rb = 0; rb < 2; ++rb)
      a[rb] = *(const short8*)&As[cur][16 * rb + l16][quad * 8];
#pragma unroll
    for (int rb = 0; rb < 2; ++rb)
#pragma unroll
      for (int cb = 0; cb < 4; ++cb)
        acc[rb][cb] = __builtin_amdgcn_mfma_f32_16x16x32_bf16(a[rb], b[cb], acc[rb][cb], 0, 0, 0);
  }

  // tanh + bias -> Ebuf (bf16). C-layout: row = 16*rb + quad*4 + r, col = 64*wave + 16*cb + l16
#pragma unroll
  for (int cb = 0; cb < 4; ++cb) {
    int col = 64 * wave + 16 * cb + l16;
    float bias = enc_b[col];
#pragma unroll
    for (int rb = 0; rb < 2; ++rb)
#pragma unroll
      for (int r = 0; r < 4; ++r) {
        int row = 16 * rb + quad * 4 + r;
        Ebuf[row][col] = f2bf(fast_tanh(acc[rb][cb][r] + bias));
      }
  }
  __syncthreads();

  // ================= GEMM2: scores = encoded @ mem^T, softmax =================
  // waves 0,1: wave covers rows [16*wave, 16*wave+16) x all 64 slots (tiny GEMM)
  if (wave < 2) {
    f32x4 acc2[4];
#pragma unroll
    for (int nb = 0; nb < 4; ++nb) acc2[nb] = (f32x4){0.f, 0.f, 0.f, 0.f};
    const int g2row = 16 * wave + l16;
#pragma unroll
    for (int kt = 0; kt < 8; ++kt) {
      int k0 = kt * 32;
      short8 a = *(const short8*)&Ebuf[g2row][k0 + quad * 8];
#pragma unroll
      for (int nb = 0; nb < 4; ++nb) {
        short8 b = *(const short8*)(memb + (16 * nb + l16) * SL_DIM + k0 + quad * 8);
        acc2[nb] = __builtin_amdgcn_mfma_f32_16x16x32_bf16(a, b, acc2[nb], 0, 0, 0);
      }
    }
#pragma unroll
    for (int r = 0; r < 4; ++r) {
      int lrow = 16 * wave + quad * 4 + r;
      float s0 = acc2[0][r] * 0.0625f, s1 = acc2[1][r] * 0.0625f;
      float s2 = acc2[2][r] * 0.0625f, s3 = acc2[3][r] * 0.0625f;
      float mx = fmaxf(fmaxf(s0, s1), fmaxf(s2, s3));
      for (int off = 1; off < 16; off <<= 1) mx = fmaxf(mx, __shfl_xor(mx, off));
      float e0 = __expf(s0 - mx), e1 = __expf(s1 - mx);
      float e2 = __expf(s2 - mx), e3 = __expf(s3 - mx);
      float sum = e0 + e1 + e2 + e3;
      for (int off = 1; off < 16; off <<= 1) sum += __shfl_xor(sum, off);
      float inv = 1.0f / sum;
      float p0 = e0 * inv, p1 = e1 * inv, p2 = e2 * inv, p3 = e3 * inv;
      size_t grow = (size_t)(r0 + lrow) * M_SLOTS;
      outA[grow + 0  + l16] = p0;  Pbuf[lrow][0  + l16] = f2bf(p0);
      outA[grow + 16 + l16] = p1;  Pbuf[lrow][16 + l16] = f2bf(p1);
      outA[grow + 32 + l16] = p2;  Pbuf[lrow][32 + l16] = f2bf(p2);
      outA[grow + 48 + l16] = p3;  Pbuf[lrow][48 + l16] = f2bf(p3);
    }
  }
  __syncthreads();

  // ================= GEMM3: memory = P @ mem  (B = memT[k][m]) =================
  // wave covers rows 0..31 x cols [64*wave, 64*wave+64)
  f32x4 acc3[2][4];
#pragma unroll
  for (int rb = 0; rb < 2; ++rb)
#pragma unroll
    for (int cb = 0; cb < 4; ++cb) acc3[rb][cb] = (f32x4){0.f, 0.f, 0.f, 0.f};
#pragma unroll
  for (int kt = 0; kt < 2; ++kt) {
    int k0 = kt * 32;
    short8 a[2], b[4];
#pragma unroll
    for (int rb = 0; rb < 2; ++rb)
      a[rb] = *(const short8*)&Pbuf[16 * rb + l16][k0 + quad * 8];
#pragma unroll
    for (int cb = 0; cb < 4; ++cb) {
      int n = 64 * wave + 16 * cb + l16;
      b[cb] = *(const short8*)(memTb + n * M_SLOTS + k0 + quad * 8);
    }
#pragma unroll
    for (int rb = 0; rb < 2; ++rb)
#pragma unroll
      for (int cb = 0; cb < 4; ++cb)
        acc3[rb][cb] = __builtin_amdgcn_mfma_f32_16x16x32_bf16(a[rb], b[cb], acc3[rb][cb], 0, 0, 0);
  }
  // write memory out (fp32) + stash bf16 into Ebuf (encoded is dead)
#pragma unroll
  for (int cb = 0; cb < 4; ++cb) {
    int col = 64 * wave + 16 * cb + l16;
#pragma unroll
    for (int rb = 0; rb < 2; ++rb)
#pragma unroll
      for (int r = 0; r < 4; ++r) {
        int row = 16 * rb + quad * 4 + r;
        float v = acc3[rb][cb][r];
        outM[(size_t)(r0 + row) * SL_DIM + col] = v;
        Ebuf[row][col] = f2bf(v);
      }
  }
  __syncthreads();

  // ================= GEMM4: recon = memory @ dec_w^T + dec_b =================
  // wave covers rows 0..31 x cols [128*wave, 128*wave+128), two 64-col halves
  for (int h = 0; h < 2; ++h) {
    const int c0 = 128 * wave + 64 * h;
    f32x4 acc4[2][4];
#pragma unroll
    for (int rb = 0; rb < 2; ++rb)
#pragma unroll
      for (int cb = 0; cb < 4; ++cb) acc4[rb][cb] = (f32x4){0.f, 0.f, 0.f, 0.f};
#pragma unroll
    for (int kt = 0; kt < 8; ++kt) {
      int k0 = kt * 32;
      short8 a[2], b[4];
#pragma unroll
      for (int rb = 0; rb < 2; ++rb)
        a[rb] = *(const short8*)&Ebuf[16 * rb + l16][k0 + quad * 8];
#pragma unroll
      for (int cb = 0; cb < 4; ++cb) {
        int n = c0 + 16 * cb + l16;
        b[cb] = *(const short8*)(decw + n * SL_DIM + k0 + quad * 8);
      }
#pragma unroll
      for (int rb = 0; rb < 2; ++rb)
#pragma unroll
        for (int cb = 0; cb < 4; ++cb)
          acc4[rb][cb] = __builtin_amdgcn_mfma_f32_16x16x32_bf16(a[rb], b[cb], acc4[rb][cb], 0, 0, 0);
    }
#pragma unroll
    for (int cb = 0; cb < 4; ++cb) {
      int col = c0 + 16 * cb + l16;
      float bias = dec_b[col];
#pragma unroll
      for (int rb = 0; rb < 2; ++rb)
#pragma unroll
        for (int r = 0; r < 4; ++r) {
          int row = 16 * rb + quad * 4 + r;
          outR[(size_t)(r0 + row) * IN_DIM + col] = acc4[rb][cb][r] + bias;
        }
    }
  }
}

extern "C" void kernel_launch(void* const* d_in, const int* in_sizes, int n_in,
                              void* d_out, int out_size, void* d_ws, size_t ws_size,
                              hipStream_t stream) {
  const float* seq   = (const float*)d_in[0];
  const float* enc_w = (const float*)d_in[1];
  const float* enc_b = (const float*)d_in[2];
  const float* mem   = (const float*)d_in[3];
  const float* dec_w = (const float*)d_in[4];
  const float* dec_b = (const float*)d_in[5];
  float* out = (float*)d_out;

  char* ws = (char*)d_ws;
  short* encb  = (short*)(ws);
  short* decb  = (short*)(ws + 262144);
  short* memb  = (short*)(ws + 524288);
  short* memTb = (short*)(ws + 557056);

  convert_weights<<<512, 256, 0, stream>>>(enc_w, dec_w, mem, encb, decb, memb, memTb);
  fused_kernel<<<2048, 256, 0, stream>>>(seq, enc_b, dec_b, encb, decb, memb, memTb, out);
}

// Round 3
// 389.480 us; speedup vs baseline: 1.1973x; 1.1973x over previous
//
#include <hip/hip_runtime.h>
#include <hip/hip_bf16.h>

#define IN_DIM  512
#define SL_DIM  256
#define M_SLOTS 64
#define TILE_R  64

typedef __attribute__((ext_vector_type(8))) short  short8;  // 8 bf16 (4 VGPRs)
typedef __attribute__((ext_vector_type(4))) float  f32x4;   // MFMA C/D

__device__ __forceinline__ short f2bf(float f) {
  union { float f; unsigned u; } v; v.f = f;
  unsigned r = (v.u + 0x7FFFu + ((v.u >> 16) & 1u)) >> 16;  // RNE
  return (short)r;
}

// packed f32x2 -> bf16x2 (v_cvt_pk_bf16_f32)
__device__ __forceinline__ unsigned cvt2(float lo, float hi) {
  union { __hip_bfloat162 h; unsigned u; } c;
  c.h = __float22bfloat162_rn(make_float2(lo, hi));
  return c.u;
}

__device__ __forceinline__ float fast_tanh(float x) {
  x = fminf(15.f, fmaxf(-15.f, x));
  float e = __expf(2.f * x);
  return (e - 1.f) / (e + 1.f);
}

// ws: enc_w bf16 [256][512] | dec_w bf16 [512][256] | mem bf16 [64][256] | memT bf16 [256][64]
__global__ void convert_weights(const float* __restrict__ enc_w,
                                const float* __restrict__ dec_w,
                                const float* __restrict__ mem,
                                short* __restrict__ encb, short* __restrict__ decb,
                                short* __restrict__ memb, short* __restrict__ memTb) {
  int i = blockIdx.x * 256 + threadIdx.x;   // grid = 512*256 = 131072 exactly
  encb[i] = f2bf(enc_w[i]);
  decb[i] = f2bf(dec_w[i]);
  if (i < M_SLOTS * SL_DIM) {
    short v = f2bf(mem[i]);
    memb[i] = v;
    memTb[(i & 255) * M_SLOTS + (i >> 8)] = v;   // memT[k][m]
  }
}

// LDS: Ebuf 33.8K + union(As dbuf 18.4K / Pbuf 9.2K) = 52.2K -> 3 blocks/CU
__global__ __launch_bounds__(256, 3) void fused_kernel(
    const float* __restrict__ seq, const float* __restrict__ enc_b,
    const float* __restrict__ dec_b, const short* __restrict__ encw,
    const short* __restrict__ decw, const short* __restrict__ memb,
    const short* __restrict__ memTb, float* __restrict__ out) {
  const int tid  = threadIdx.x;
  const int wave = tid >> 6;
  const int lane = tid & 63;
  const int l16  = lane & 15;
  const int quad = lane >> 4;
  const int r0   = blockIdx.x * TILE_R;

  __shared__ __align__(16) short Ebuf[TILE_R][SL_DIM + 8];   // encoded, later memory (bf16)
  // As (GEMM1 A-staging, dead after GEMM1) overlapped with Pbuf (born in GEMM2)
  __shared__ __align__(16) union {
    short As[2][TILE_R][72];        // double-buffered K=64 slice, +8 pad
    short Pbuf[TILE_R][M_SLOTS + 8];
  } U;

  float* __restrict__ outR = out;              // reconstruction [65536][512]
  float* __restrict__ outA = out + 33554432;   // attention      [65536][64]
  float* __restrict__ outM = out + 37748736;   // memory         [65536][256]

  // ================= GEMM1: encoded = tanh(seq @ enc_w^T + b) =================
  // wave covers rows 0..63 x cols [64*wave, 64*wave+64)
  // 8 K-steps of 64, double-buffered LDS, ONE barrier per step.
  f32x4 acc[4][4];
#pragma unroll
  for (int rb = 0; rb < 4; ++rb)
#pragma unroll
    for (int cb = 0; cb < 4; ++cb) acc[rb][cb] = (f32x4){0.f, 0.f, 0.f, 0.f};

  const int srow = tid >> 2;          // 0..63
  const int skc  = (tid & 3) * 16;    // 0,16,32,48 (floats within K=64 slice)
  const float* sp = seq + (size_t)(r0 + srow) * IN_DIM + skc;
  const short* bP[4];
#pragma unroll
  for (int cb = 0; cb < 4; ++cb)
    bP[cb] = encw + (64 * wave + 16 * cb + l16) * IN_DIM + quad * 8;

  float4 v[4];
  // prologue: load + write step-0 slice into As[0], then issue step-1 loads
#pragma unroll
  for (int j = 0; j < 4; ++j) v[j] = *(const float4*)(sp + 4 * j);
  {
    uint4 w0, w1;
    w0.x = cvt2(v[0].x, v[0].y); w0.y = cvt2(v[0].z, v[0].w);
    w0.z = cvt2(v[1].x, v[1].y); w0.w = cvt2(v[1].z, v[1].w);
    w1.x = cvt2(v[2].x, v[2].y); w1.y = cvt2(v[2].z, v[2].w);
    w1.z = cvt2(v[3].x, v[3].y); w1.w = cvt2(v[3].z, v[3].w);
    *(uint4*)&U.As[0][srow][skc]     = w0;
    *(uint4*)&U.As[0][srow][skc + 8] = w1;
  }
#pragma unroll
  for (int j = 0; j < 4; ++j) v[j] = *(const float4*)(sp + 64 + 4 * j);

  for (int kt = 0; kt < 8; ++kt) {
    const int cur = kt & 1;
    __syncthreads();                   // As[cur] visible; As[cur^1] reads (kt-1) done
    if (kt < 7) {                      // write slice kt+1 (regs drained by barrier)
      uint4 w0, w1;
      w0.x = cvt2(v[0].x, v[0].y); w0.y = cvt2(v[0].z, v[0].w);
      w0.z = cvt2(v[1].x, v[1].y); w0.w = cvt2(v[1].z, v[1].w);
      w1.x = cvt2(v[2].x, v[2].y); w1.y = cvt2(v[2].z, v[2].w);
      w1.z = cvt2(v[3].x, v[3].y); w1.w = cvt2(v[3].z, v[3].w);
      *(uint4*)&U.As[cur ^ 1][srow][skc]     = w0;
      *(uint4*)&U.As[cur ^ 1][srow][skc + 8] = w1;
    }
    if (kt < 6) {                      // issue slice kt+2 loads; drain at NEXT barrier
#pragma unroll
      for (int j = 0; j < 4; ++j) v[j] = *(const float4*)(sp + (kt + 2) * 64 + 4 * j);
    }
#pragma unroll
    for (int ks = 0; ks < 2; ++ks) {
      const int k0 = kt * 64 + ks * 32;
      short8 a[4], b[4];
#pragma unroll
      for (int cb = 0; cb < 4; ++cb)
        b[cb] = *(const short8*)(bP[cb] + k0);
#pragma unroll
      for (int rb = 0; rb < 4; ++rb)
        a[rb] = *(const short8*)&U.As[cur][16 * rb + l16][ks * 32 + quad * 8];
#pragma unroll
      for (int rb = 0; rb < 4; ++rb)
#pragma unroll
        for (int cb = 0; cb < 4; ++cb)
          acc[rb][cb] = __builtin_amdgcn_mfma_f32_16x16x32_bf16(a[rb], b[cb], acc[rb][cb], 0, 0, 0);
    }
  }

  // tanh + bias -> Ebuf (bf16). C-layout: row = 16*rb + quad*4 + r, col = 64*wave + 16*cb + l16
#pragma unroll
  for (int cb = 0; cb < 4; ++cb) {
    int col = 64 * wave + 16 * cb + l16;
    float bias = enc_b[col];
#pragma unroll
    for (int rb = 0; rb < 4; ++rb)
#pragma unroll
      for (int r = 0; r < 4; ++r) {
        int row = 16 * rb + quad * 4 + r;
        Ebuf[row][col] = f2bf(fast_tanh(acc[rb][cb][r] + bias));
      }
  }
  __syncthreads();

  // ================= GEMM2: scores = encoded @ mem^T, softmax =================
  // wave covers rows [16*wave, 16*wave+16) x all 64 slots
  f32x4 acc2[4];
#pragma unroll
  for (int nb = 0; nb < 4; ++nb) acc2[nb] = (f32x4){0.f, 0.f, 0.f, 0.f};
  const int g2row = 16 * wave + l16;
#pragma unroll
  for (int kt = 0; kt < 8; ++kt) {
    int k0 = kt * 32;
    short8 a = *(const short8*)&Ebuf[g2row][k0 + quad * 8];
#pragma unroll
    for (int nb = 0; nb < 4; ++nb) {
      short8 b = *(const short8*)(memb + (16 * nb + l16) * SL_DIM + k0 + quad * 8);
      acc2[nb] = __builtin_amdgcn_mfma_f32_16x16x32_bf16(a, b, acc2[nb], 0, 0, 0);
    }
  }
#pragma unroll
  for (int r = 0; r < 4; ++r) {
    int lrow = 16 * wave + quad * 4 + r;
    float s0 = acc2[0][r] * 0.0625f, s1 = acc2[1][r] * 0.0625f;
    float s2 = acc2[2][r] * 0.0625f, s3 = acc2[3][r] * 0.0625f;
    float mx = fmaxf(fmaxf(s0, s1), fmaxf(s2, s3));
    for (int off = 1; off < 16; off <<= 1) mx = fmaxf(mx, __shfl_xor(mx, off));
    float e0 = __expf(s0 - mx), e1 = __expf(s1 - mx);
    float e2 = __expf(s2 - mx), e3 = __expf(s3 - mx);
    float sum = e0 + e1 + e2 + e3;
    for (int off = 1; off < 16; off <<= 1) sum += __shfl_xor(sum, off);
    float inv = 1.0f / sum;
    float p0 = e0 * inv, p1 = e1 * inv, p2 = e2 * inv, p3 = e3 * inv;
    size_t grow = (size_t)(r0 + lrow) * M_SLOTS;
    outA[grow + 0  + l16] = p0;  U.Pbuf[lrow][0  + l16] = f2bf(p0);
    outA[grow + 16 + l16] = p1;  U.Pbuf[lrow][16 + l16] = f2bf(p1);
    outA[grow + 32 + l16] = p2;  U.Pbuf[lrow][32 + l16] = f2bf(p2);
    outA[grow + 48 + l16] = p3;  U.Pbuf[lrow][48 + l16] = f2bf(p3);
  }
  __syncthreads();

  // ================= GEMM3: memory = P @ mem  (B = memT[k][m]) =================
  // wave covers rows 0..63 x cols [64*wave, 64*wave+64)
  f32x4 acc3[4][4];
#pragma unroll
  for (int rb = 0; rb < 4; ++rb)
#pragma unroll
    for (int cb = 0; cb < 4; ++cb) acc3[rb][cb] = (f32x4){0.f, 0.f, 0.f, 0.f};
#pragma unroll
  for (int kt = 0; kt < 2; ++kt) {
    int k0 = kt * 32;
    short8 a[4], b[4];
#pragma unroll
    for (int rb = 0; rb < 4; ++rb)
      a[rb] = *(const short8*)&U.Pbuf[16 * rb + l16][k0 + quad * 8];
#pragma unroll
    for (int cb = 0; cb < 4; ++cb) {
      int n = 64 * wave + 16 * cb + l16;
      b[cb] = *(const short8*)(memTb + n * M_SLOTS + k0 + quad * 8);
    }
#pragma unroll
    for (int rb = 0; rb < 4; ++rb)
#pragma unroll
      for (int cb = 0; cb < 4; ++cb)
        acc3[rb][cb] = __builtin_amdgcn_mfma_f32_16x16x32_bf16(a[rb], b[cb], acc3[rb][cb], 0, 0, 0);
  }
  // write memory out (fp32) + stash bf16 into Ebuf (encoded is dead)
#pragma unroll
  for (int cb = 0; cb < 4; ++cb) {
    int col = 64 * wave + 16 * cb + l16;
#pragma unroll
    for (int rb = 0; rb < 4; ++rb)
#pragma unroll
      for (int r = 0; r < 4; ++r) {
        int row = 16 * rb + quad * 4 + r;
        float v2 = acc3[rb][cb][r];
        outM[(size_t)(r0 + row) * SL_DIM + col] = v2;
        Ebuf[row][col] = f2bf(v2);
      }
  }
  __syncthreads();

  // ================= GEMM4: recon = memory @ dec_w^T + dec_b =================
  // wave covers rows 0..63 x cols [128*wave, 128*wave+128), two 64-col halves
  for (int h = 0; h < 2; ++h) {
    const int c0 = 128 * wave + 64 * h;
    f32x4 acc4[4][4];
#pragma unroll
    for (int rb = 0; rb < 4; ++rb)
#pragma unroll
      for (int cb = 0; cb < 4; ++cb) acc4[rb][cb] = (f32x4){0.f, 0.f, 0.f, 0.f};
#pragma unroll
    for (int kt = 0; kt < 8; ++kt) {
      int k0 = kt * 32;
      short8 a[4], b[4];
#pragma unroll
      for (int rb = 0; rb < 4; ++rb)
        a[rb] = *(const short8*)&Ebuf[16 * rb + l16][k0 + quad * 8];
#pragma unroll
      for (int cb = 0; cb < 4; ++cb) {
        int n = c0 + 16 * cb + l16;
        b[cb] = *(const short8*)(decw + n * SL_DIM + k0 + quad * 8);
      }
#pragma unroll
      for (int rb = 0; rb < 4; ++rb)
#pragma unroll
        for (int cb = 0; cb < 4; ++cb)
          acc4[rb][cb] = __builtin_amdgcn_mfma_f32_16x16x32_bf16(a[rb], b[cb], acc4[rb][cb], 0, 0, 0);
    }
#pragma unroll
    for (int cb = 0; cb < 4; ++cb) {
      int col = c0 + 16 * cb + l16;
      float bias = dec_b[col];
#pragma unroll
      for (int rb = 0; rb < 4; ++rb)
#pragma unroll
        for (int r = 0; r < 4; ++r) {
          int row = 16 * rb + quad * 4 + r;
          outR[(size_t)(r0 + row) * IN_DIM + col] = acc4[rb][cb][r] + bias;
        }
    }
  }
}

extern "C" void kernel_launch(void* const* d_in, const int* in_sizes, int n_in,
                              void* d_out, int out_size, void* d_ws, size_t ws_size,
                              hipStream_t stream) {
  const float* seq   = (const float*)d_in[0];
  const float* enc_w = (const float*)d_in[1];
  const float* enc_b = (const float*)d_in[2];
  const float* mem   = (const float*)d_in[3];
  const float* dec_w = (const float*)d_in[4];
  const float* dec_b = (const float*)d_in[5];
  float* out = (float*)d_out;

  char* ws = (char*)d_ws;
  short* encb  = (short*)(ws);
  short* decb  = (short*)(ws + 262144);
  short* memb  = (short*)(ws + 524288);
  short* memTb = (short*)(ws + 557056);

  convert_weights<<<512, 256, 0, stream>>>(enc_w, dec_w, mem, encb, decb, memb, memTb);
  fused_kernel<<<1024, 256, 0, stream>>>(seq, enc_b, dec_b, encb, decb, memb, memTb, out);
}